// Round 1
// baseline (212.200 us; speedup 1.0000x reference)
//
#include <hip/hip_runtime.h>

#define T_SEQ 4096
#define NDIM 64
#define BH 32

typedef short short8 __attribute__((ext_vector_type(8)));
typedef float f32x16 __attribute__((ext_vector_type(16)));

static __device__ __forceinline__ unsigned short f2bf(float x) {
    union { float f; unsigned u; } v; v.f = x;
    return (unsigned short)((v.u + 0x8000u) >> 16);
}

static __device__ __forceinline__ f32x16 mfma32(short8 a, short8 b, f32x16 c) {
    return __builtin_amdgcn_mfma_f32_32x32x16_bf16(a, b, c, 0, 0, 0);
}

// ---------------- Kernel 1: RoPE(Q) -> bf16 qr[bh][t][64] ----------------
__global__ __launch_bounds__(256) void rope_kernel(const float* __restrict__ Q,
                                                   unsigned short* __restrict__ qr) {
    int p = blockIdx.x * 256 + threadIdx.x;          // pair index, B*H*T*32 total
    const int total = BH * T_SEQ * 32;
    if (p >= total) return;
    int np = p & 31;                                  // pair within head-dim
    int t  = (p >> 5) & (T_SEQ - 1);
    float2 q = ((const float2*)Q)[p];
    // freq = theta^(-tq/N)/(2pi), theta=2^16, tq=2*np, N=64 -> 2^(-np/2)/(2pi)
    float freq = exp2f(-0.5f * (float)np) * 0.15915494309189535f;
    float ph = (float)t * freq;
    float ang = (ph - floorf(ph)) * 6.283185307179586f;
    float s, c;
    __sincosf(ang, &s, &c);
    float r0 = q.x * c - q.y * s;
    float r1 = q.y * c + q.x * s;
    unsigned pk = (unsigned)f2bf(r0) | ((unsigned)f2bf(r1) << 16);
    ((unsigned*)qr)[p] = pk;
}

// ------- Kernel 2: V -> bf16 vt[bh][d][t], pre-scaled by N^-0.5 = 0.125 -------
__global__ __launch_bounds__(256) void vtrans_kernel(const float* __restrict__ V,
                                                     unsigned short* __restrict__ vt) {
    __shared__ float tile[64][65];
    int bh = blockIdx.y;
    int s0 = blockIdx.x * 64;
    const float* vsrc = V + ((size_t)bh * T_SEQ + s0) * NDIM;
    int tid = threadIdx.x;
#pragma unroll
    for (int i = 0; i < 4; ++i) {
        int e = (i * 256 + tid) * 4;
        int row = e >> 6, col = e & 63;
        float4 d4 = *(const float4*)(vsrc + e);
        tile[row][col + 0] = d4.x; tile[row][col + 1] = d4.y;
        tile[row][col + 2] = d4.z; tile[row][col + 3] = d4.w;
    }
    __syncthreads();
    unsigned short* vdst = vt + (size_t)bh * NDIM * T_SEQ + s0;
#pragma unroll
    for (int i = 0; i < 4; ++i) {
        int e = (i * 256 + tid) * 4;
        int d = e >> 6, sc = e & 63;
        ushort4 o;
        o.x = f2bf(tile[sc + 0][d] * 0.125f);
        o.y = f2bf(tile[sc + 1][d] * 0.125f);
        o.z = f2bf(tile[sc + 2][d] * 0.125f);
        o.w = f2bf(tile[sc + 3][d] * 0.125f);
        *(ushort4*)(vdst + (size_t)d * T_SEQ + sc) = o;
    }
}

// ---------------- Kernel 3: main masked attention (no softmax) ----------------
// Per block: one (bh, 128-row q-tile). 4 waves. S = QR*QR^T via 32x32x16 bf16 MFMA,
// P (=S, V pre-scaled) round-trips through LDS, O += P*V with V frags from global vt.
#define LDK 72    // 64 + 8 pad (bf16 elems), 16B-aligned rows
#define LDP 136   // 128 + 8 pad

__global__ __launch_bounds__(256, 2) void attn_kernel(const unsigned short* __restrict__ qr,
                                                      const unsigned short* __restrict__ vt,
                                                      float* __restrict__ out) {
    __shared__ unsigned short ks[128 * LDK];   // K-tile (rows of RoPE'd Q)
    __shared__ unsigned short ps[128 * LDP];   // P tile bf16

    const int tid = threadIdx.x;
    const int lane = tid & 63;
    const int w = tid >> 6;
    const int wm = w >> 1, wn = w & 1;
    const int l31 = lane & 31, hi = lane >> 5;

    const int blk = blockIdx.x;
    const int bh = blk & 31;
    const int qb = 31 - (blk >> 5);          // longest blocks first
    const int t0 = qb * 128;

    const unsigned short* qr_h = qr + (size_t)bh * (T_SEQ * NDIM);
    const unsigned short* vt_h = vt + (size_t)bh * (NDIM * T_SEQ);
    float* out_h = out + (size_t)bh * (T_SEQ * NDIM);

    // Preload Q A-fragments for this wave's two m-tiles (persist across s-blocks)
    short8 aq[2][4];
#pragma unroll
    for (int mt2 = 0; mt2 < 2; ++mt2)
#pragma unroll
        for (int kc = 0; kc < 4; ++kc)
            aq[mt2][kc] = *(const short8*)(qr_h +
                (size_t)(t0 + (2 * wm + mt2) * 32 + l31) * NDIM + kc * 16 + hi * 8);

    f32x16 oacc[2];
#pragma unroll
    for (int m = 0; m < 2; ++m)
#pragma unroll
        for (int r = 0; r < 16; ++r) oacc[m][r] = 0.0f;

    for (int sb = 0; sb <= qb; ++sb) {
        const int s0 = sb * 128;

        // V B-fragments from global (L2-resident), independent of LDS — issue early
        short8 vf[8];
#pragma unroll
        for (int kc = 0; kc < 8; ++kc)
            vf[kc] = *(const short8*)(vt_h + (size_t)(wn * 32 + l31) * T_SEQ +
                                      s0 + kc * 16 + hi * 8);

        // Stage K-tile: 128x64 bf16, coalesced 16B copies
#pragma unroll
        for (int i = 0; i < 4; ++i) {
            int e = (i * 256 + tid) * 8;
            int row = e >> 6, col = e & 63;
            *(short8*)&ks[row * LDK + col] =
                *(const short8*)(qr_h + (size_t)s0 * NDIM + e);
        }
        __syncthreads();

        // ---- S-phase: sacc[mt2][nt2] = Q_tile * K_tile^T ----
        f32x16 sacc[2][2];
#pragma unroll
        for (int a = 0; a < 2; ++a)
#pragma unroll
            for (int b = 0; b < 2; ++b)
#pragma unroll
                for (int r = 0; r < 16; ++r) sacc[a][b][r] = 0.0f;

        short8 bf[2][4];
#pragma unroll
        for (int nt2 = 0; nt2 < 2; ++nt2)
#pragma unroll
            for (int kc = 0; kc < 4; ++kc)
                bf[nt2][kc] = *(const short8*)&ks[((2 * wn + nt2) * 32 + l31) * LDK +
                                                  kc * 16 + hi * 8];
#pragma unroll
        for (int mt2 = 0; mt2 < 2; ++mt2)
#pragma unroll
            for (int nt2 = 0; nt2 < 2; ++nt2)
#pragma unroll
                for (int kc = 0; kc < 4; ++kc)
                    sacc[mt2][nt2] = mfma32(aq[mt2][kc], bf[nt2][kc], sacc[mt2][nt2]);

        // ---- write P to LDS (mask strictly-lower on diagonal block) ----
        const bool diag = (sb == qb);
#pragma unroll
        for (int mt2 = 0; mt2 < 2; ++mt2) {
            const int mt = 2 * wm + mt2;
#pragma unroll
            for (int nt2 = 0; nt2 < 2; ++nt2) {
                const int nt = 2 * wn + nt2;
                const int scol = nt * 32 + l31;
#pragma unroll
                for (int r = 0; r < 16; ++r) {
                    const int rl = (r & 3) + 8 * (r >> 2) + 4 * hi;
                    const int trow = mt * 32 + rl;
                    float v = sacc[mt2][nt2][r];
                    if (diag && scol >= trow) v = 0.0f;   // keep s < t only
                    ps[trow * LDP + scol] = f2bf(v);
                }
            }
        }
        __syncthreads();

        // ---- O-phase: oacc += P * V ----
#pragma unroll
        for (int kc = 0; kc < 8; ++kc) {
            short8 pf0 = *(const short8*)&ps[((2 * wm + 0) * 32 + l31) * LDP +
                                             kc * 16 + hi * 8];
            short8 pf1 = *(const short8*)&ps[((2 * wm + 1) * 32 + l31) * LDP +
                                             kc * 16 + hi * 8];
            oacc[0] = mfma32(pf0, vf[kc], oacc[0]);
            oacc[1] = mfma32(pf1, vf[kc], oacc[1]);
        }
        __syncthreads();   // ps reads done before next iteration rewrites ks/ps
    }

    // ---- epilogue: fp32 store, C-layout ----
#pragma unroll
    for (int mt2 = 0; mt2 < 2; ++mt2) {
        const int mt = 2 * wm + mt2;
#pragma unroll
        for (int r = 0; r < 16; ++r) {
            const int rl = (r & 3) + 8 * (r >> 2) + 4 * hi;
            out_h[(size_t)(t0 + mt * 32 + rl) * NDIM + wn * 32 + l31] = oacc[mt2][r];
        }
    }
}

extern "C" void kernel_launch(void* const* d_in, const int* in_sizes, int n_in,
                              void* d_out, int out_size, void* d_ws, size_t ws_size,
                              hipStream_t stream) {
    (void)in_sizes; (void)n_in; (void)out_size; (void)ws_size;
    const float* Q = (const float*)d_in[0];
    const float* V = (const float*)d_in[1];
    float* out = (float*)d_out;

    unsigned short* qr = (unsigned short*)d_ws;            // 16 MB bf16
    unsigned short* vt = qr + (size_t)BH * T_SEQ * NDIM;   // 16 MB bf16

    const int total_pairs = BH * T_SEQ * 32;
    rope_kernel<<<(total_pairs + 255) / 256, 256, 0, stream>>>(Q, qr);
    vtrans_kernel<<<dim3(T_SEQ / 64, BH), 256, 0, stream>>>(V, vt);
    attn_kernel<<<BH * 32, 256, 0, stream>>>(qr, vt, out);
}